// Round 9
// baseline (43.631 us; speedup 1.0000x reference)
//
#include <hip/hip_runtime.h>

typedef float f32x4 __attribute__((ext_vector_type(4)));

#define NBP 128   // partial-max blocks per table

// ---- pass 1: per-block partial maxes, f32x4 loads ----
__global__ __launch_bounds__(256) void table_max_partial(
        const float* __restrict__ tx,
        const float* __restrict__ ty,
        int n4 /* n_table/4 */,
        float* __restrict__ px,
        float* __restrict__ py) {
    const bool isx = (int)blockIdx.x < NBP;
    const f32x4* t = (const f32x4*)(isx ? tx : ty);
    float* dst = isx ? px : py;
    const int b = isx ? blockIdx.x : blockIdx.x - NBP;
    const int stride = NBP * 256;
    float m = -INFINITY;
    for (int i = b * 256 + threadIdx.x; i < n4; i += stride) {
        const f32x4 v = t[i];
        m = fmaxf(m, fmaxf(fmaxf(v.x, v.y), fmaxf(v.z, v.w)));
    }
    #pragma unroll
    for (int off = 32; off > 0; off >>= 1)
        m = fmaxf(m, __shfl_down(m, off, 64));
    __shared__ float sm[4];
    const int lane = threadIdx.x & 63, wid = threadIdx.x >> 6;
    if (lane == 0) sm[wid] = m;
    __syncthreads();
    if (threadIdx.x == 0)
        dst[b] = fmaxf(fmaxf(sm[0], sm[1]), fmaxf(sm[2], sm[3]));
}

// ---- block-wide reduce of partials -> (sx, sy); NBP=128 <= blockDim ----
__device__ void reduce_scales(const float* __restrict__ px,
                              const float* __restrict__ py,
                              float& sx, float& sy) {
    float mx = (threadIdx.x < NBP) ? px[threadIdx.x] : -INFINITY;
    float my = (threadIdx.x < NBP) ? py[threadIdx.x] : -INFINITY;
    #pragma unroll
    for (int off = 32; off > 0; off >>= 1) {
        mx = fmaxf(mx, __shfl_down(mx, off, 64));
        my = fmaxf(my, __shfl_down(my, off, 64));
    }
    __shared__ float smx[4], smy[4];
    const int lane = threadIdx.x & 63, wid = threadIdx.x >> 6;
    if (lane == 0) { smx[wid] = mx; smy[wid] = my; }
    __syncthreads();
    sx = 0.1f / fmaxf(fmaxf(smx[0], smx[1]), fmaxf(smx[2], smx[3]));
    sy = 0.1f / fmaxf(fmaxf(smy[0], smy[1]), fmaxf(smy[2], smy[3]));
}

// ---- pass 2: build combined tables, f32x4 per thread ----
__global__ __launch_bounds__(256) void build_kernel(
        const float* __restrict__ fixedt,
        const float* __restrict__ tx,
        const float* __restrict__ ty,
        const float* __restrict__ px,
        const float* __restrict__ py,
        f32x4* __restrict__ cx, f32x4* __restrict__ cy,
        int total16 /* rows*16 */) {
    float sx, sy;
    reduce_scales(px, py, sx, sy);
    const f32x4* fx4 = (const f32x4*)fixedt;
    const f32x4* tx4 = (const f32x4*)tx;
    const f32x4* ty4 = (const f32x4*)ty;
    const int stride = gridDim.x * blockDim.x;
    for (int i = blockIdx.x * blockDim.x + threadIdx.x; i < total16; i += stride) {
        const f32x4 f0 = fx4[2 * i], f1 = fx4[2 * i + 1];
        const f32x4 x0 = tx4[2 * i], x1 = tx4[2 * i + 1];
        const f32x4 y0 = ty4[2 * i], y1 = ty4[2 * i + 1];
        f32x4 cxv, cyv;
        cxv.x = sx * (x0.x + x0.y) + (f0.x + f0.y);
        cxv.y = sx * (x0.z + x0.w) + (f0.z + f0.w);
        cxv.z = sx * (x1.x + x1.y) + (f1.x + f1.y);
        cxv.w = sx * (x1.z + x1.w) + (f1.z + f1.w);
        cyv.x = sy * (y0.x + y0.y) + (f0.x + f0.y);
        cyv.y = sy * (y0.z + y0.w) + (f0.z + f0.w);
        cyv.z = sy * (y1.x + y1.y) + (f1.x + f1.y);
        cyv.w = sy * (y1.z + y1.w) + (f1.z + f1.w);
        cx[i] = cxv;
        cy[i] = cyv;
    }
}

// ---- pass 3: gather, 4-deep software pipeline, PLAIN stores ----
// float4 index i: row = i>>5, q = i&31 (stride % 32 == 0 -> q invariant).
__global__ __launch_bounds__(256) void gather_kernel(
        const int* __restrict__ pos,
        const f32x4* __restrict__ cx,
        const f32x4* __restrict__ cy,
        f32x4* __restrict__ out, int total4) {
    const int stride = gridDim.x * blockDim.x;      // multiple of 32
    const int i0 = blockIdx.x * blockDim.x + threadIdx.x;
    const int  q    = i0 & 31;
    const bool isx  = (q < 16);
    const f32x4* __restrict__ tab = (isx ? cx : cy) + (isx ? q : q - 16);
    const int  poff = isx ? 0 : 1;
    const int  rowstep = stride >> 5;

    int i = i0;
    int row = i0 >> 5;
    for (; i + 3 * stride < total4; i += 4 * stride, row += 4 * rowstep) {
        // 4 independent pos loads
        int p0 = pos[2 * (row + 0 * rowstep) + poff];
        int p1 = pos[2 * (row + 1 * rowstep) + poff];
        int p2 = pos[2 * (row + 2 * rowstep) + poff];
        int p3 = pos[2 * (row + 3 * rowstep) + poff];
        p0 = (p0 < 0) ? 1 : p0;  p1 = (p1 < 0) ? 1 : p1;
        p2 = (p2 < 0) ? 1 : p2;  p3 = (p3 < 0) ? 1 : p3;
        // 4 independent table loads (L2-hit)
        const f32x4 v0 = tab[p0 * 16];
        const f32x4 v1 = tab[p1 * 16];
        const f32x4 v2 = tab[p2 * 16];
        const f32x4 v3 = tab[p3 * 16];
        // 4 plain streaming stores
        out[i + 0 * stride] = v0;
        out[i + 1 * stride] = v1;
        out[i + 2 * stride] = v2;
        out[i + 3 * stride] = v3;
    }
    for (; i < total4; i += stride, row += rowstep) {
        int p = pos[2 * row + poff];
        if (p < 0) p = 1;
        out[i] = tab[p * 16];
    }
}

extern "C" void kernel_launch(void* const* d_in, const int* in_sizes, int n_in,
                              void* d_out, int out_size, void* d_ws, size_t ws_size,
                              hipStream_t stream) {
    const int*   pos    = (const int*)  d_in[0];   // [16,512,32,2]
    const float* fixedt = (const float*)d_in[1];   // [table_len,128]
    const float* tx     = (const float*)d_in[2];
    const float* ty     = (const float*)d_in[3];
    f32x4* out = (f32x4*)d_out;

    const int n_table  = in_sizes[2];              // table_len * 128
    const int rows     = n_table >> 7;             // table_len
    const int total4   = out_size >> 2;

    // ws layout: px[NBP], py[NBP], then cx[rows*16], cy[rows*16] f32x4 (16B aligned)
    float* px = (float*)d_ws;
    float* py = px + NBP;
    f32x4* cx = (f32x4*)(py + NBP);
    f32x4* cy = cx + (size_t)rows * 16;

    table_max_partial<<<2 * NBP, 256, 0, stream>>>(tx, ty, n_table >> 2, px, py);

    const int btot16 = rows * 16;
    build_kernel<<<(btot16 + 255) / 256, 256, 0, stream>>>(fixedt, tx, ty, px, py,
                                                           cx, cy, btot16);
    gather_kernel<<<2048, 256, 0, stream>>>(pos, (const f32x4*)cx, (const f32x4*)cy,
                                            out, total4);
}